// Round 3
// baseline (108.977 us; speedup 1.0000x reference)
//
#include <hip/hip_runtime.h>

#define NPTS 512      // N rows
#define INS  512      // INSIZE
#define KDIM 64       // K groups
#define DDIM 16       // D per group
#define CDIM (KDIM*DDIM)  // 1024 linear output cols
#define OUTC (INS + KDIM) // 576
#define KSPLIT 8
#define FEAT_ELEMS ((size_t)NPTS * CDIM)   // 524288 floats per split buffer
#define FEAT_F4    (FEAT_ELEMS / 4)        // 131072 float4 per split

__device__ __forceinline__ float exp2_fast(float x) {
    return __builtin_amdgcn_exp2f(x);
}

__device__ __forceinline__ void fma2(float2& acc, float s, float x, float y) {
    acc.x = __builtin_fmaf(s, x, acc.x);
    acc.y = __builtin_fmaf(s, y, acc.y);
}

// ---------------- Kernel A: raw partial feat = x @ W^T over a 64-wide K-slice.
// tile 64i x 64c, micro-tile 4i x 4c. grid (16 ctile, 8 itile, 8 ksplit) = 1024 blocks.
__global__ __launch_bounds__(256) void gemm_kernel(
    const float* __restrict__ x,    // [512][512]
    const float* __restrict__ W,    // [1024][512]
    float* __restrict__ featT)      // KSPLIT x [64][512][16]
{
    const int tid = threadIdx.x;
    const int cbase = blockIdx.x * 64;
    const int ibase = blockIdx.y * 64;
    const int kbase = blockIdx.z * (INS / KSPLIT);  // 64-wide K-slice

    __shared__ float xs[16][68];   // [kk][i], 68%32=4 -> 2-way max (free)
    __shared__ float wss[16][68];  // [kk][c]

    const int tx = tid & 15;   // c micro: cbase + tx*4
    const int ty = tid >> 4;   // i micro: ibase + ty*4
    const int kkL = tid & 15;
    const int rL  = tid >> 4;

    float2 acc[4][2] = {};     // [ii][c-pair]  (packed for v_pk_fma_f32)

    for (int k0 = kbase; k0 < kbase + INS / KSPLIT; k0 += 16) {
        #pragma unroll
        for (int q = 0; q < 4; ++q) {
            xs[kkL][rL + 16 * q]  = x[(ibase + rL + 16 * q) * INS + k0 + kkL];
            wss[kkL][rL + 16 * q] = W[(cbase + rL + 16 * q) * INS + k0 + kkL];
        }
        __syncthreads();

        #pragma unroll
        for (int kk = 0; kk < 16; ++kk) {
            float4 a = *(const float4*)&xs[kk][ty * 4];
            float4 w = *(const float4*)&wss[kk][tx * 4];
            fma2(acc[0][0], a.x, w.x, w.y);  fma2(acc[0][1], a.x, w.z, w.w);
            fma2(acc[1][0], a.y, w.x, w.y);  fma2(acc[1][1], a.y, w.z, w.w);
            fma2(acc[2][0], a.z, w.x, w.y);  fma2(acc[2][1], a.z, w.z, w.w);
            fma2(acc[3][0], a.w, w.x, w.y);  fma2(acc[3][1], a.w, w.z, w.w);
        }
        __syncthreads();
    }

    const int c = cbase + tx * 4;
    const int k = c >> 4;
    const int d = c & 15;
    float* dst = featT + (size_t)blockIdx.z * FEAT_ELEMS;
    #pragma unroll
    for (int ii = 0; ii < 4; ++ii) {
        const int i = ibase + ty * 4 + ii;
        float4 v = make_float4(acc[ii][0].x, acc[ii][0].y, acc[ii][1].x, acc[ii][1].y);
        *(float4*)&dst[((size_t)k * NPTS + i) * DDIM + d] = v;
    }
}

// ---------------- Kernel B (fused): blocks [0,512): featR = (sum of 8 splits + bias)*log2e
//                                   blocks [512,800): out[:, :512]=x ; out[:, 512:]=-1
__global__ __launch_bounds__(256) void fuse_reduce_init_kernel(
    const float* __restrict__ featT,  // 8 split buffers, contiguous
    const float* __restrict__ bias,   // [1024]
    const float* __restrict__ x,      // [512][512]
    float* __restrict__ featR,        // [64][512][16]
    float* __restrict__ out)          // [512][576]
{
    const int b = blockIdx.x;
    if (b < 512) {
        const int f4 = b * 256 + threadIdx.x;     // 0..131071
        const float4* s = (const float4*)featT;
        float4 p0 = s[f4];
        float4 p1 = s[f4 + 1 * FEAT_F4];
        float4 p2 = s[f4 + 2 * FEAT_F4];
        float4 p3 = s[f4 + 3 * FEAT_F4];
        float4 p4 = s[f4 + 4 * FEAT_F4];
        float4 p5 = s[f4 + 5 * FEAT_F4];
        float4 p6 = s[f4 + 6 * FEAT_F4];
        float4 p7 = s[f4 + 7 * FEAT_F4];
        const int k = f4 >> 11;                   // 2048 float4 per k-slice
        const float4 bq = ((const float4*)bias)[(k << 2) + (f4 & 3)];
        const float LOG2E = 1.4426950408889634f;
        float4 r;
        r.x = (((p0.x + p1.x) + (p2.x + p3.x)) + ((p4.x + p5.x) + (p6.x + p7.x)) + bq.x) * LOG2E;
        r.y = (((p0.y + p1.y) + (p2.y + p3.y)) + ((p4.y + p5.y) + (p6.y + p7.y)) + bq.y) * LOG2E;
        r.z = (((p0.z + p1.z) + (p2.z + p3.z)) + ((p4.z + p5.z) + (p6.z + p7.z)) + bq.z) * LOG2E;
        r.w = (((p0.w + p1.w) + (p2.w + p3.w)) + ((p4.w + p5.w) + (p6.w + p7.w)) + bq.w) * LOG2E;
        ((float4*)featR)[f4] = r;
    } else {
        const int idx = (b - 512) * 256 + threadIdx.x;  // 0..73727 float4 of out
        const int i  = idx / (OUTC / 4);
        const int j4 = idx - i * (OUTC / 4);
        float4 v;
        if (j4 < INS / 4) v = ((const float4*)x)[i * (INS / 4) + j4];
        else              v = make_float4(-1.0f, -1.0f, -1.0f, -1.0f);
        ((float4*)out)[idx] = v;
    }
}

// ---------------- Kernel C: o_b accumulation. 4 i's per lane.
// grid (64 k, 2 itile(256 i), 8 jq(64 j)) = 1024 blocks. Wave wv sweeps 16 j's.
__global__ __launch_bounds__(256, 4) void pairwise_kernel(
    const float* __restrict__ featR,  // [64][512][16], pre-scaled by log2e
    float* __restrict__ out)          // [512][576]
{
    const int k     = blockIdx.x;
    const int itile = blockIdx.y;
    const int jq    = blockIdx.z;

    __shared__ float fj[64 * DDIM];    // 4 KB
    __shared__ float part[4][256];     // 4 KB

    // stage 64 j-features: 256 float4, one per thread
    ((float4*)fj)[threadIdx.x] =
        ((const float4*)(featR + ((size_t)k * NPTS + jq * 64) * DDIM))[threadIdx.x];

    const int lane = threadIdx.x & 63;
    const int wv   = threadIdx.x >> 6;

    float fi[4][16];
    #pragma unroll
    for (int u = 0; u < 4; ++u) {
        const int i = itile * 256 + u * 64 + lane;
        const float4* p = (const float4*)(featR + ((size_t)k * NPTS + i) * DDIM);
        float4 v0 = p[0], v1 = p[1], v2 = p[2], v3 = p[3];
        fi[u][0]=v0.x;  fi[u][1]=v0.y;  fi[u][2]=v0.z;  fi[u][3]=v0.w;
        fi[u][4]=v1.x;  fi[u][5]=v1.y;  fi[u][6]=v1.z;  fi[u][7]=v1.w;
        fi[u][8]=v2.x;  fi[u][9]=v2.y;  fi[u][10]=v2.z; fi[u][11]=v2.w;
        fi[u][12]=v3.x; fi[u][13]=v3.y; fi[u][14]=v3.z; fi[u][15]=v3.w;
    }
    __syncthreads();

    float acc[4] = {0.f, 0.f, 0.f, 0.f};
    const float* fp = fj + wv * 16 * DDIM;
    #pragma unroll 2
    for (int jj = 0; jj < 16; ++jj) {
        const float* p = fp + jj * DDIM;
        float4 q0 = *(const float4*)(p);
        float4 q1 = *(const float4*)(p + 4);
        float4 q2 = *(const float4*)(p + 8);
        float4 q3 = *(const float4*)(p + 12);
        #pragma unroll
        for (int u = 0; u < 4; ++u) {
            float a0 = fabsf(fi[u][0]  - q0.x) + fabsf(fi[u][1]  - q0.y)
                     + fabsf(fi[u][2]  - q0.z) + fabsf(fi[u][3]  - q0.w);
            float a1 = fabsf(fi[u][4]  - q1.x) + fabsf(fi[u][5]  - q1.y)
                     + fabsf(fi[u][6]  - q1.z) + fabsf(fi[u][7]  - q1.w);
            float a2 = fabsf(fi[u][8]  - q2.x) + fabsf(fi[u][9]  - q2.y)
                     + fabsf(fi[u][10] - q2.z) + fabsf(fi[u][11] - q2.w);
            float a3 = fabsf(fi[u][12] - q3.x) + fabsf(fi[u][13] - q3.y)
                     + fabsf(fi[u][14] - q3.z) + fabsf(fi[u][15] - q3.w);
            acc[u] += exp2_fast(-((a0 + a1) + (a2 + a3)));
        }
    }

    #pragma unroll
    for (int u = 0; u < 4; ++u)
        part[wv][u * 64 + lane] = acc[u];
    __syncthreads();

    {
        const int t = threadIdx.x;
        float s = (part[0][t] + part[1][t]) + (part[2][t] + part[3][t]);
        const int i = itile * 256 + t;
        atomicAdd(&out[(size_t)i * OUTC + INS + k], s);
    }
}

extern "C" void kernel_launch(void* const* d_in, const int* in_sizes, int n_in,
                              void* d_out, int out_size, void* d_ws, size_t ws_size,
                              hipStream_t stream) {
    const float* x    = (const float*)d_in[0];
    const float* W    = (const float*)d_in[1];
    const float* bias = (const float*)d_in[2];
    float* out = (float*)d_out;
    float* featT = (float*)d_ws;                       // 8 x 2 MB split buffers
    float* featR = featT + KSPLIT * FEAT_ELEMS;        // 2 MB reduced buffer

    gemm_kernel<<<dim3(CDIM / 64, NPTS / 64, KSPLIT), 256, 0, stream>>>(x, W, featT);
    fuse_reduce_init_kernel<<<dim3(512 + NPTS * (OUTC / 4) / 256), 256, 0, stream>>>(
        featT, bias, x, featR, out);
    pairwise_kernel<<<dim3(KDIM, 2, 8), 256, 0, stream>>>(featR, out);
}

// Round 4
// 100.963 us; speedup vs baseline: 1.0794x; 1.0794x over previous
//
#include <hip/hip_runtime.h>

#define NPTS 512      // N rows
#define INS  512      // INSIZE
#define KDIM 64       // K groups
#define DDIM 16       // D per group
#define CDIM (KDIM*DDIM)   // 1024 linear output cols
#define OUTC (INS + KDIM)  // 576
#define KSPLIT 4
#define FEAT_ELEMS ((size_t)NPTS * CDIM)   // 524288 floats per split buffer
#define LOG2E 1.4426950408889634f

typedef short short8 __attribute__((ext_vector_type(8)));   // 8 bf16 (4 VGPRs)
typedef float f32x4  __attribute__((ext_vector_type(4)));   // MFMA acc

__device__ __forceinline__ float exp2_fast(float x) {
    return __builtin_amdgcn_exp2f(x);
}

// round-to-nearest-even fp32 -> bf16 (inputs are normal Gaussians; no NaN/Inf)
__device__ __forceinline__ unsigned int f2bf(float f) {
    unsigned int x = __float_as_uint(f);
    return (x + 0x7fffu + ((x >> 16) & 1u)) >> 16;
}

// convert 8 consecutive fp32 at src into packed bf16x8 (uint4)
__device__ __forceinline__ uint4 cvt8(const float* src) {
    float4 lo = *(const float4*)src;
    float4 hi = *(const float4*)(src + 4);
    uint4 v;
    v.x = f2bf(lo.x) | (f2bf(lo.y) << 16);
    v.y = f2bf(lo.z) | (f2bf(lo.w) << 16);
    v.z = f2bf(hi.x) | (f2bf(hi.y) << 16);
    v.w = f2bf(hi.z) | (f2bf(hi.w) << 16);
    return v;
}

// ---------------- Kernel 1: prepack x,W into bf16 fragment-chunk layout
//   xP[kc][i]  (kc=0..63 chunk of 8 k, i=0..511)   : frag = x[i][kc*8 .. +7]
//   WP[kc][c]  (c=0..1023)                          : frag = W[c][kc*8 .. +7]
// plus out init: out[:, :512] = x, out[:, 512:] = -1 (absorbs diagonal's +1)
__global__ __launch_bounds__(256) void prepack_kernel(
    const float* __restrict__ x, const float* __restrict__ W,
    uint4* __restrict__ xP, uint4* __restrict__ WP, float* __restrict__ out)
{
    const int b = blockIdx.x;
    if (b < 128) {                      // 32768 threads: xP
        const int t = b * 256 + threadIdx.x;
        const int kc = t & 63, i = t >> 6;
        xP[kc * NPTS + i] = cvt8(x + i * INS + kc * 8);
    } else if (b < 384) {               // 65536 threads: WP
        const int t = (b - 128) * 256 + threadIdx.x;
        const int kc = t & 63, c = t >> 6;
        WP[kc * CDIM + c] = cvt8(W + c * INS + kc * 8);
    } else {                            // 73728 float4: out init
        const int idx = (b - 384) * 256 + threadIdx.x;
        const int i  = idx / (OUTC / 4);
        const int j4 = idx - i * (OUTC / 4);
        float4 v;
        if (j4 < INS / 4) v = ((const float4*)x)[i * (INS / 4) + j4];
        else              v = make_float4(-1.0f, -1.0f, -1.0f, -1.0f);
        ((float4*)out)[idx] = v;
    }
}

// ---------------- Kernel 2: bf16 MFMA GEMM, tile 64i x 64c, k-slice 128.
// grid (16 ctile, 8 itile, 4 ksplit) = 512 blocks, 256 thr (4 waves).
// wave w owns c-strip [cbase + w*16, +16); 4 m-blocks of 16 i.
// Epilogue writes featT[ks][k][i][d] = (acc [+ bias]) * log2e (fp32).
__global__ __launch_bounds__(256) void mfma_gemm_kernel(
    const uint4* __restrict__ xP, const uint4* __restrict__ WP,
    const float* __restrict__ bias, float* __restrict__ featT)
{
    __shared__ uint4 As[16 * 64];   // [kc][i]  16 KB
    __shared__ uint4 Bs[16 * 64];   // [kc][c]  16 KB

    const int tid   = threadIdx.x;
    const int cbase = blockIdx.x * 64;
    const int ibase = blockIdx.y * 64;
    const int kc0   = blockIdx.z * 16;   // 16 chunks = 128 k

    #pragma unroll
    for (int r = 0; r < 4; ++r) {
        const int idx = r * 256 + tid;       // 0..1023
        const int kc = idx >> 6, col = idx & 63;
        As[idx] = xP[(kc0 + kc) * NPTS + ibase + col];
        Bs[idx] = WP[(kc0 + kc) * CDIM + cbase + col];
    }
    __syncthreads();

    const int lane = tid & 63, wv = tid >> 6;
    const int quad = lane >> 4, ln = lane & 15;

    f32x4 acc[4];
    #pragma unroll
    for (int mi = 0; mi < 4; ++mi) acc[mi] = (f32x4){0.f, 0.f, 0.f, 0.f};

    #pragma unroll
    for (int t = 0; t < 4; ++t) {            // 4 k-steps of 32
        uint4 bu = Bs[(t * 4 + quad) * 64 + wv * 16 + ln];
        short8 bf = *(short8*)&bu;
        #pragma unroll
        for (int mi = 0; mi < 4; ++mi) {
            uint4 au = As[(t * 4 + quad) * 64 + mi * 16 + ln];
            short8 af = *(short8*)&au;
            acc[mi] = __builtin_amdgcn_mfma_f32_16x16x32_bf16(af, bf, acc[mi], 0, 0, 0);
        }
    }

    // C/D layout: col (c) = lane&15, row (i) = quad*4 + reg
    const int kg = (cbase >> 4) + wv;        // wave-uniform k-group 0..63
    float badd = 0.f;
    if (blockIdx.z == 0) badd = bias[cbase + wv * 16 + ln];
    float* dst = featT + (size_t)blockIdx.z * FEAT_ELEMS
               + ((size_t)kg * NPTS) * DDIM + ln;
    #pragma unroll
    for (int mi = 0; mi < 4; ++mi) {
        #pragma unroll
        for (int reg = 0; reg < 4; ++reg) {
            const int i = ibase + mi * 16 + quad * 4 + reg;
            dst[(size_t)i * DDIM] = (acc[mi][reg] + badd) * LOG2E;
        }
    }
}

// identical summation order for fi and fj staging => diagonal diff is exactly 0
__device__ __forceinline__ float4 sum4(const float4* s0, const float4* s1,
                                       const float4* s2, const float4* s3, size_t g) {
    float4 a = s0[g], b = s1[g], c = s2[g], d = s3[g];
    float4 r;
    r.x = (a.x + b.x) + (c.x + d.x);
    r.y = (a.y + b.y) + (c.y + d.y);
    r.z = (a.z + b.z) + (c.z + d.z);
    r.w = (a.w + b.w) + (c.w + d.w);
    return r;
}

// ---------------- Kernel 3: o_b accumulation. 4 i's/lane, fi staged via LDS
// in lane-contiguous layout fiL[(u*4+q)*64 + lane] (conflict-free b128 reads).
// grid (64 k, 2 itile(256 i), 8 jq(64 j)) = 1024 blocks; wave sweeps 16 j's.
__global__ __launch_bounds__(256, 4) void pairwise_kernel(
    const float* __restrict__ f0, const float* __restrict__ f1,
    const float* __restrict__ f2, const float* __restrict__ f3,
    float* __restrict__ out)
{
    const int k     = blockIdx.x;
    const int itile = blockIdx.y;
    const int jq    = blockIdx.z;

    __shared__ float4 fj4[64 * 4];     // 4 KB  [j][q]
    __shared__ float4 fiL[16 * 64];    // 16 KB [(u*4+q)][lane]
    __shared__ float  part[4][256];    // 4 KB

    const float4* s0 = (const float4*)f0;
    const float4* s1 = (const float4*)f1;
    const float4* s2 = (const float4*)f2;
    const float4* s3 = (const float4*)f3;

    // stage fj: 64 j x 16 d = 256 float4, one per thread
    {
        const size_t g = ((size_t)k * NPTS + jq * 64) * 4 + threadIdx.x;
        fj4[threadIdx.x] = sum4(s0, s1, s2, s3, g);
    }
    // stage fi: 256 i x 16 d = 1024 float4, transposed into lane-contiguous rows
    {
        const size_t base = ((size_t)k * NPTS + itile * 256) * 4;
        #pragma unroll
        for (int r = 0; r < 4; ++r) {
            const int idx = r * 256 + threadIdx.x;
            const int il = idx >> 2, q = idx & 3;
            fiL[((il >> 6) * 4 + q) * 64 + (il & 63)] = sum4(s0, s1, s2, s3, base + idx);
        }
    }
    __syncthreads();

    const int lane = threadIdx.x & 63;
    const int wv   = threadIdx.x >> 6;

    float fi[4][16];
    #pragma unroll
    for (int u = 0; u < 4; ++u) {
        #pragma unroll
        for (int q = 0; q < 4; ++q) {
            float4 v = fiL[(u * 4 + q) * 64 + lane];
            fi[u][q * 4 + 0] = v.x; fi[u][q * 4 + 1] = v.y;
            fi[u][q * 4 + 2] = v.z; fi[u][q * 4 + 3] = v.w;
        }
    }

    float acc[4] = {0.f, 0.f, 0.f, 0.f};
    const float4* fp = fj4 + wv * 16 * 4;
    #pragma unroll 2
    for (int jj = 0; jj < 16; ++jj) {
        float4 q0 = fp[jj * 4 + 0];
        float4 q1 = fp[jj * 4 + 1];
        float4 q2 = fp[jj * 4 + 2];
        float4 q3 = fp[jj * 4 + 3];
        #pragma unroll
        for (int u = 0; u < 4; ++u) {
            float a0 = fabsf(fi[u][0]  - q0.x) + fabsf(fi[u][1]  - q0.y)
                     + fabsf(fi[u][2]  - q0.z) + fabsf(fi[u][3]  - q0.w);
            float a1 = fabsf(fi[u][4]  - q1.x) + fabsf(fi[u][5]  - q1.y)
                     + fabsf(fi[u][6]  - q1.z) + fabsf(fi[u][7]  - q1.w);
            float a2 = fabsf(fi[u][8]  - q2.x) + fabsf(fi[u][9]  - q2.y)
                     + fabsf(fi[u][10] - q2.z) + fabsf(fi[u][11] - q2.w);
            float a3 = fabsf(fi[u][12] - q3.x) + fabsf(fi[u][13] - q3.y)
                     + fabsf(fi[u][14] - q3.z) + fabsf(fi[u][15] - q3.w);
            acc[u] += exp2_fast(-((a0 + a1) + (a2 + a3)));
        }
    }

    #pragma unroll
    for (int u = 0; u < 4; ++u)
        part[wv][u * 64 + lane] = acc[u];
    __syncthreads();

    {
        const int t = threadIdx.x;
        float s = (part[0][t] + part[1][t]) + (part[2][t] + part[3][t]);
        const int i = itile * 256 + t;
        atomicAdd(&out[(size_t)i * OUTC + INS + k], s);
    }
}

extern "C" void kernel_launch(void* const* d_in, const int* in_sizes, int n_in,
                              void* d_out, int out_size, void* d_ws, size_t ws_size,
                              hipStream_t stream) {
    const float* x    = (const float*)d_in[0];
    const float* W    = (const float*)d_in[1];
    const float* bias = (const float*)d_in[2];
    float* out = (float*)d_out;

    float* featT = (float*)d_ws;                                   // 4 x 2 MB splits
    uint4* xP = (uint4*)(featT + KSPLIT * FEAT_ELEMS);             // 512 KB
    uint4* WP = xP + 64 * NPTS;                                    // 1 MB

    prepack_kernel<<<dim3(672), 256, 0, stream>>>(x, W, xP, WP, out);
    mfma_gemm_kernel<<<dim3(16, 8, 4), 256, 0, stream>>>(xP, WP, bias, featT);
    pairwise_kernel<<<dim3(KDIM, 2, 8), 256, 0, stream>>>(
        featT, featT + FEAT_ELEMS, featT + 2 * FEAT_ELEMS, featT + 3 * FEAT_ELEMS, out);
}

// Round 5
// 98.593 us; speedup vs baseline: 1.1053x; 1.0240x over previous
//
#include <hip/hip_runtime.h>

#define NPTS 512      // N rows
#define INS  512      // INSIZE
#define KDIM 64       // K groups
#define DDIM 16       // D per group
#define CDIM (KDIM*DDIM)   // 1024 linear output cols
#define OUTC (INS + KDIM)  // 576
#define LOG2E 1.4426950408889634f

typedef short short8 __attribute__((ext_vector_type(8)));   // 8 bf16 (4 VGPRs)
typedef float f32x4  __attribute__((ext_vector_type(4)));   // MFMA acc

__device__ __forceinline__ float exp2_fast(float x) {
    return __builtin_amdgcn_exp2f(x);
}

// round-to-nearest-even fp32 -> bf16
__device__ __forceinline__ unsigned int f2bf(float f) {
    unsigned int x = __float_as_uint(f);
    return (x + 0x7fffu + ((x >> 16) & 1u)) >> 16;
}

// 8 consecutive fp32 -> packed bf16x8 (uint4)
__device__ __forceinline__ uint4 cvt8(const float* src) {
    float4 lo = *(const float4*)src;
    float4 hi = *(const float4*)(src + 4);
    uint4 v;
    v.x = f2bf(lo.x) | (f2bf(lo.y) << 16);
    v.y = f2bf(lo.z) | (f2bf(lo.w) << 16);
    v.z = f2bf(hi.x) | (f2bf(hi.y) << 16);
    v.w = f2bf(hi.z) | (f2bf(hi.w) << 16);
    return v;
}

// ---------------- Kernel 1: prepack x,W to bf16 fragment-chunk layout + out init
//   xP[kc][i] (kc: chunk of 8 k), WP[kc][c]; out[:, :512]=x, out[:, 512:]=-1
__global__ __launch_bounds__(256) void prepack_kernel(
    const float* __restrict__ x, const float* __restrict__ W,
    uint4* __restrict__ xP, uint4* __restrict__ WP, float* __restrict__ out)
{
    const int b = blockIdx.x;
    if (b < 128) {                      // 32768 threads: xP
        const int t = b * 256 + threadIdx.x;
        const int kc = t & 63, i = t >> 6;
        xP[kc * NPTS + i] = cvt8(x + i * INS + kc * 8);
    } else if (b < 384) {               // 65536 threads: WP
        const int t = (b - 128) * 256 + threadIdx.x;
        const int kc = t & 63, c = t >> 6;
        WP[kc * CDIM + c] = cvt8(W + c * INS + kc * 8);
    } else {                            // 73728 float4: out init
        const int idx = (b - 384) * 256 + threadIdx.x;
        const int i  = idx / (OUTC / 4);
        const int j4 = idx - i * (OUTC / 4);
        float4 v;
        if (j4 < INS / 4) v = ((const float4*)x)[i * (INS / 4) + j4];
        else              v = make_float4(-1.0f, -1.0f, -1.0f, -1.0f);  // absorbs diagonal's +1
        ((float4*)out)[idx] = v;
    }
}

// ---------------- Kernel 2: single-pass bf16 MFMA GEMM, tile 32i x 32c, FULL K=512.
// grid (32 ctile, 16 itile) = 512 blocks (2/CU), 256 thr (4 waves).
// All of K staged once (A 32KB + B 32KB LDS), ONE barrier, then 16 ds+MFMA steps.
// Wave wv owns 16x16 C-block (mi=wv&1, ci=wv>>1).
// Epilogue: featR[kg][i][d] = (acc + bias)*log2e (final, no split/reduce).
__global__ __launch_bounds__(256) void mfma_gemm_kernel(
    const uint4* __restrict__ xP, const uint4* __restrict__ WP,
    const float* __restrict__ bias, float* __restrict__ featR)
{
    __shared__ uint4 As[64 * 32];   // [kc][i]  32 KB
    __shared__ uint4 Bs[64 * 32];   // [kc][c]  32 KB

    const int tid   = threadIdx.x;
    const int cbase = blockIdx.x * 32;
    const int ibase = blockIdx.y * 32;

    #pragma unroll
    for (int r = 0; r < 8; ++r) {
        const int idx = r * 256 + tid;       // 0..2047
        const int kc = idx >> 5, col = idx & 31;
        As[idx] = xP[kc * NPTS + ibase + col];
        Bs[idx] = WP[kc * CDIM + cbase + col];
    }
    __syncthreads();

    const int lane = tid & 63, wv = tid >> 6;
    const int quad = lane >> 4, ln = lane & 15;
    const int mi = wv & 1, ci = wv >> 1;

    f32x4 acc = (f32x4){0.f, 0.f, 0.f, 0.f};
    #pragma unroll
    for (int t = 0; t < 16; ++t) {           // 16 k-steps of 32
        short8 af = *(short8*)&As[(t * 4 + quad) * 32 + mi * 16 + ln];
        short8 bf = *(short8*)&Bs[(t * 4 + quad) * 32 + ci * 16 + ln];
        acc = __builtin_amdgcn_mfma_f32_16x16x32_bf16(af, bf, acc, 0, 0, 0);
    }

    // C/D layout: col (c) = lane&15, row (i) = quad*4 + reg
    const int c  = cbase + ci * 16 + ln;     // d = c & 15 == ln
    const int kg = c >> 4;
    const float badd = bias[c];
    float* dst = featR + ((size_t)kg * NPTS) * DDIM + ln;
    #pragma unroll
    for (int reg = 0; reg < 4; ++reg) {
        const int i = ibase + mi * 16 + quad * 4 + reg;
        dst[(size_t)i * DDIM] = (acc[reg] + badd) * LOG2E;
    }
}

// ---------------- Kernel 3: o_b accumulation. 4 i's/lane, single featR buffer.
// grid (64 k, 2 itile(256 i), 8 jq(64 j)) = 1024 blocks; wave sweeps 16 j's.
__global__ __launch_bounds__(256, 4) void pairwise_kernel(
    const float* __restrict__ featR,  // [64][512][16], pre-scaled by log2e
    float* __restrict__ out)          // [512][576]
{
    const int k     = blockIdx.x;
    const int itile = blockIdx.y;
    const int jq    = blockIdx.z;

    __shared__ float4 fj4[64 * 4];     // 4 KB [j][q]
    __shared__ float  part[4][256];    // 4 KB

    // stage fj: 64 j x 16 d = 256 float4, one per thread (straight copy)
    fj4[threadIdx.x] =
        ((const float4*)featR)[((size_t)k * NPTS + jq * 64) * 4 + threadIdx.x];

    const int lane = threadIdx.x & 63;
    const int wv   = threadIdx.x >> 6;

    float fi[4][16];
    #pragma unroll
    for (int u = 0; u < 4; ++u) {
        const int i = itile * 256 + u * 64 + lane;
        const float4* p = (const float4*)(featR + ((size_t)k * NPTS + i) * DDIM);
        float4 v0 = p[0], v1 = p[1], v2 = p[2], v3 = p[3];
        fi[u][0]=v0.x;  fi[u][1]=v0.y;  fi[u][2]=v0.z;  fi[u][3]=v0.w;
        fi[u][4]=v1.x;  fi[u][5]=v1.y;  fi[u][6]=v1.z;  fi[u][7]=v1.w;
        fi[u][8]=v2.x;  fi[u][9]=v2.y;  fi[u][10]=v2.z; fi[u][11]=v2.w;
        fi[u][12]=v3.x; fi[u][13]=v3.y; fi[u][14]=v3.z; fi[u][15]=v3.w;
    }
    __syncthreads();

    float acc[4] = {0.f, 0.f, 0.f, 0.f};
    const float4* fp = fj4 + wv * 16 * 4;
    #pragma unroll 2
    for (int jj = 0; jj < 16; ++jj) {
        float4 q0 = fp[jj * 4 + 0];
        float4 q1 = fp[jj * 4 + 1];
        float4 q2 = fp[jj * 4 + 2];
        float4 q3 = fp[jj * 4 + 3];
        #pragma unroll
        for (int u = 0; u < 4; ++u) {
            float a0 = fabsf(fi[u][0]  - q0.x) + fabsf(fi[u][1]  - q0.y)
                     + fabsf(fi[u][2]  - q0.z) + fabsf(fi[u][3]  - q0.w);
            float a1 = fabsf(fi[u][4]  - q1.x) + fabsf(fi[u][5]  - q1.y)
                     + fabsf(fi[u][6]  - q1.z) + fabsf(fi[u][7]  - q1.w);
            float a2 = fabsf(fi[u][8]  - q2.x) + fabsf(fi[u][9]  - q2.y)
                     + fabsf(fi[u][10] - q2.z) + fabsf(fi[u][11] - q2.w);
            float a3 = fabsf(fi[u][12] - q3.x) + fabsf(fi[u][13] - q3.y)
                     + fabsf(fi[u][14] - q3.z) + fabsf(fi[u][15] - q3.w);
            acc[u] += exp2_fast(-((a0 + a1) + (a2 + a3)));
        }
    }

    #pragma unroll
    for (int u = 0; u < 4; ++u)
        part[wv][u * 64 + lane] = acc[u];
    __syncthreads();

    {
        const int t = threadIdx.x;
        float s = (part[0][t] + part[1][t]) + (part[2][t] + part[3][t]);
        const int i = itile * 256 + t;
        atomicAdd(&out[(size_t)i * OUTC + INS + k], s);
    }
}

extern "C" void kernel_launch(void* const* d_in, const int* in_sizes, int n_in,
                              void* d_out, int out_size, void* d_ws, size_t ws_size,
                              hipStream_t stream) {
    const float* x    = (const float*)d_in[0];
    const float* W    = (const float*)d_in[1];
    const float* bias = (const float*)d_in[2];
    float* out = (float*)d_out;

    float* featR = (float*)d_ws;                        // 2 MB final features
    uint4* xP = (uint4*)(featR + (size_t)NPTS * CDIM);  // 512 KB bf16-packed x
    uint4* WP = xP + 64 * NPTS;                         // 1 MB bf16-packed W

    prepack_kernel<<<dim3(672), 256, 0, stream>>>(x, W, xP, WP, out);
    mfma_gemm_kernel<<<dim3(CDIM / 32, NPTS / 32), 256, 0, stream>>>(xP, WP, bias, featR);
    pairwise_kernel<<<dim3(KDIM, 2, 8), 256, 0, stream>>>(featR, out);
}